// Round 20
// baseline (215.588 us; speedup 1.0000x reference)
//
#include <hip/hip_runtime.h>
#include <hip/hip_bf16.h>

typedef __hip_bfloat16 bf16;
typedef unsigned short u16;
typedef __attribute__((ext_vector_type(8))) short  b8v;    // 8 bf16 bits (4 VGPR) MFMA operand
typedef __attribute__((ext_vector_type(8))) unsigned short u16x8;
typedef __attribute__((ext_vector_type(4))) unsigned short u16x4;
typedef __attribute__((ext_vector_type(4))) float f32x4;

static __device__ __forceinline__ float us2f(u16 s) {
    unsigned int u = ((unsigned int)s) << 16;
    return __builtin_bit_cast(float, u);
}
static __device__ __forceinline__ u16 f2us(float x) {
    union { bf16 h; u16 s; } v; v.h = __float2bfloat16(x); return v.s;
}
static __device__ __forceinline__ float b2f(bf16 x) { return __bfloat162float(x); }
static __device__ __forceinline__ bf16 f2b(float x) { return __float2bfloat16(x); }

// async global->LDS, 16 bytes/lane. Dest is wave-uniform base + lane*16;
// global source IS per-lane (m173 pre-swizzled-source pattern).
static __device__ __forceinline__ void gload16(const u16* g, u16* l) {
    __builtin_amdgcn_global_load_lds(
        (const __attribute__((address_space(1))) unsigned int*)g,
        (__attribute__((address_space(3))) unsigned int*)l,
        16, 0, 0);
}

// ---------------- prep kernels ----------------

__global__ __launch_bounds__(256) void cast_f2b4(const float* __restrict__ src,
                                                 u16* __restrict__ dst, int n4)
{
    int i = blockIdx.x * 256 + threadIdx.x;
    if (i < n4) {
        float4 v = ((const float4*)src)[i];
        u16x4 o = { f2us(v.x), f2us(v.y), f2us(v.z), f2us(v.w) };
        ((u16x4*)dst)[i] = o;
    }
}

// src[M][P] f32 -> dst[P][M] bf16, 64x64 LDS tiles (also used for Wq transpose)
__global__ __launch_bounds__(256) void transpose_cast_x(const float* __restrict__ x,
                                                        u16* __restrict__ xT, int C, int P)
{
    __shared__ u16 t[64][72];
    const int b = blockIdx.z, c0 = blockIdx.y * 64, p0 = blockIdx.x * 64;
    const int tid = threadIdx.x;
    const int r = tid >> 2, q = tid & 3;
    const float* src = x + ((size_t)b * C + c0 + r) * P + p0 + q * 16;
#pragma unroll
    for (int i = 0; i < 16; i++) t[q * 16 + i][r] = f2us(src[i]);
    __syncthreads();
    u16* dst = xT + ((size_t)b * P + p0 + r) * C + c0 + q * 16;
    *(u16x8*)dst       = *(u16x8*)&t[r][q * 16];
    *(u16x8*)(dst + 8) = *(u16x8*)&t[r][q * 16 + 8];
}

// fused post-h1 prep: conv2 weight repack (blocks 0..2303), c3w cast (2304..2367),
// h1p halo zero (2368..2627). All independent, all needed before conv/out.
__global__ __launch_bounds__(256) void prep2(const float* __restrict__ c2w,
                                             u16* __restrict__ c2w_b,
                                             const float* __restrict__ c3w,
                                             u16* __restrict__ c3w_b,
                                             u16* __restrict__ h1p)
{
    const int blk = blockIdx.x;
    if (blk < 2304) {
        int idx = blk * 256 + threadIdx.x;          // 256*2304
        int o = idx / 2304, k = idx - o * 2304;
        int tap = k >> 8, c = k & 255;
        c2w_b[idx] = f2us(c2w[(o * 256 + c) * 9 + tap]);
    } else if (blk < 2368) {
        int i = (blk - 2304) * 256 + threadIdx.x;   // 16384 float4
        float4 v = ((const float4*)c3w)[i];
        u16x4 o = { f2us(v.x), f2us(v.y), f2us(v.z), f2us(v.w) };
        ((u16x4*)c3w_b)[i] = o;
    } else {
        int i = (blk - 2368) * 256 + threadIdx.x;   // 8*260*32
        const int ch8 = i & 31; i >>= 5;
        const int hp = i % 260;
        const int b = i / 260;
        int py, px;
        if (hp < 66)       { py = 0;  px = hp; }
        else if (hp < 132) { py = 65; px = hp - 66; }
        else if (hp < 196) { py = hp - 132 + 1; px = 0; }
        else               { py = hp - 196 + 1; px = 65; }
        u16x8 z = {0, 0, 0, 0, 0, 0, 0, 0};
        *(u16x8*)&h1p[(((size_t)b * 66 + py) * 66 + px) * 256 + ch8 * 8] = z;
    }
}

// ---------------- fused K/V projection (K=32 VALU GEMM, one launch) ----------------
// z = b + 8*isV: out[b][n][c] = sum_g graph[b][n][g] * W[c][g] + bias[c]
__global__ __launch_bounds__(256) void kv_proj(
    const float* __restrict__ graph,
    const float* __restrict__ Wk, const float* __restrict__ bk,
    const float* __restrict__ Wv, const float* __restrict__ bv,
    bf16* __restrict__ Kt, bf16* __restrict__ Vt, int N, int C, int G)
{
    const int z = blockIdx.z;
    const int b = z & 7;
    const bool isv = (z >> 3) != 0;
    const float* W    = isv ? Wv : Wk;
    const float* bias = isv ? bv : bk;
    bf16* Out         = isv ? Vt : Kt;
    __shared__ float As[16][65];
    __shared__ float Bs[16][65];
    const float* Ab = graph + (long)b * N * G;
    const int m0 = blockIdx.y * 64, n0 = blockIdx.x * 64;
    const int tid = threadIdx.x;
    const int tx = tid & 15, ty = tid >> 4;
    float acc[4][4] = {};

    for (int k0 = 0; k0 < G; k0 += 16) {
#pragma unroll
        for (int i = 0; i < 4; i++) {
            int idx = tid + i * 256; int kk = idx & 15, mm = idx >> 4;
            As[kk][mm] = Ab[(long)(m0 + mm) * G + k0 + kk];
        }
#pragma unroll
        for (int i = 0; i < 4; i++) {
            int idx = tid + i * 256; int kk = idx & 15, nn = idx >> 4;
            Bs[kk][nn] = W[(long)(n0 + nn) * G + k0 + kk];
        }
        __syncthreads();
#pragma unroll
        for (int kk = 0; kk < 16; kk++) {
            float a[4], bb[4];
#pragma unroll
            for (int i = 0; i < 4; i++) a[i]  = As[kk][ty * 4 + i];
#pragma unroll
            for (int j = 0; j < 4; j++) bb[j] = Bs[kk][tx * 4 + j];
#pragma unroll
            for (int i = 0; i < 4; i++)
#pragma unroll
                for (int j = 0; j < 4; j++) acc[i][j] += a[i] * bb[j];
        }
        __syncthreads();
    }
#pragma unroll
    for (int i = 0; i < 4; i++) {
        int m = m0 + ty * 4 + i;
#pragma unroll
        for (int j = 0; j < 4; j++) {
            int n = n0 + tx * 4 + j;
            Out[(long)b * N * C + (long)m * C + n] = f2b(acc[i][j] + bias[n]);
        }
    }
}

// ---------------- MFMA GEMM (m97 + T2 XOR swizzle + BK=64; NO XCD swizzle) ----------------
// C[m][n] = epi( scale * sum_k A[m][k] * Bt[n][k] ); A,Bt k-contiguous bf16-bits.
// BK=64 double-plane staging: per iteration, 8 gload_lds fill two 32-k planes,
// then ONE barrier pair covers 2 MFMA sub-steps (halves barrier-drain count).
// LDS rows 32 u16; chunk c of row r stored at c ^ ((r>>1)&3) via pre-swizzled
// per-lane GLOBAL source (rule 21). Reads 2-way max.
// T1 XCD swizzle REMOVED this round: all operands are L3-resident (<=64 MiB;
// L3 = 256 MiB) and m160 shows the swizzle costs ~2% in the L3-fit regime;
// identity mapping also keeps same-A-panel blocks adjacent per XCD.
// EPI: 0 scale+bias[m]; 1 BN+LeakyReLU (CT: padded [66][66][C] store);
//      3 exp((acc + bias[bat*N+n]) * scale), LDS-transposed u16x8 stores
//        (tbuf aliases the staging LDS, dead after K-loop), col partials -> csum;
//      4 (CT) fp32 float4 store: v*scale + bias[n] + resid[n][mb..mb+3]
template<int EPI, bool CT, typename TC, int NTILE>
__global__ __launch_bounds__(256) void gemm_mfma(
    const u16* __restrict__ A, const u16* __restrict__ Bt, TC* __restrict__ Cc,
    int M, int N, int K, int lda, int ldb, int ldc,
    long aBat, long bBat, long cBat,
    float scale, const float* __restrict__ bias,
    const float* __restrict__ gamma, const float* __restrict__ beta,
    const float* __restrict__ mean,  const float* __restrict__ var,
    const float* __restrict__ resid, long rBat, int ldr,
    float* __restrict__ csum)
{
    constexpr int NI = NTILE / 32;          // B fragments per wave
    constexpr int AW = 128 * 32;            // A plane size in u16
    constexpr int BW = NTILE * 32;          // B plane size in u16
    __shared__ u16 lds[2][AW + BW];         // [plane][A | B]
    __shared__ float red[(EPI == 3) ? 256 : 1];
    const int bat = blockIdx.z;
    const int bidx = blockIdx.x, bidy = blockIdx.y;   // identity (no XCD swizzle)
    const int m0 = bidy * 128, n0 = bidx * NTILE;
    const int tid = threadIdx.x;
    const int lane = tid & 63, wid = tid >> 6;
    const int wr = wid >> 1, wc = wid & 1;
    const int fr = lane & 15, fq = lane >> 4;
    const int sc = ((lane & 3) ^ ((lane >> 3) & 3)) * 8;   // pre-swizzled source chunk
    const int axs = (fq ^ ((fr >> 1) & 3)) * 8;            // swizzled read chunk

    const u16* gA = A  + (size_t)bat * aBat + (size_t)(m0 + wid * 32 + (lane >> 2)) * lda + sc;
    const u16* gB = Bt + (size_t)bat * bBat + (size_t)(n0 + wid * (NTILE / 4) + (lane >> 2)) * ldb + sc;
    const int aoff = (wid * 32) * 32;
    const int boff = AW + (wid * (NTILE / 4)) * 32;
    const size_t a16 = (size_t)16 * lda, b16 = (size_t)16 * ldb;

    f32x4 acc[4][NI];
#pragma unroll
    for (int i = 0; i < 4; i++)
#pragma unroll
        for (int j = 0; j < NI; j++) acc[i][j] = (f32x4){0.f, 0.f, 0.f, 0.f};

    for (int k0 = 0; k0 < K; k0 += 64) {
        gload16(gA + k0,            &lds[0][aoff]);
        gload16(gA + k0 + a16,      &lds[0][aoff + 16 * 32]);
        gload16(gA + k0 + 32,       &lds[1][aoff]);
        gload16(gA + k0 + 32 + a16, &lds[1][aoff + 16 * 32]);
        gload16(gB + k0,            &lds[0][boff]);
        if constexpr (NTILE == 128) gload16(gB + k0 + b16, &lds[0][boff + 16 * 32]);
        gload16(gB + k0 + 32,       &lds[1][boff]);
        if constexpr (NTILE == 128) gload16(gB + k0 + 32 + b16, &lds[1][boff + 16 * 32]);
        __syncthreads();
#pragma unroll
        for (int t = 0; t < 2; t++) {
            b8v a[4], b[NI];
#pragma unroll
            for (int mi = 0; mi < 4; mi++)
                a[mi] = *(const b8v*)&lds[t][(wr * 64 + mi * 16 + fr) * 32 + axs];
#pragma unroll
            for (int ni = 0; ni < NI; ni++)
                b[ni] = *(const b8v*)&lds[t][AW + (wc * (NTILE / 2) + ni * 16 + fr) * 32 + axs];
#pragma unroll
            for (int mi = 0; mi < 4; mi++)
#pragma unroll
                for (int ni = 0; ni < NI; ni++)
                    acc[mi][ni] = __builtin_amdgcn_mfma_f32_16x16x32_bf16(a[mi], b[ni], acc[mi][ni], 0, 0, 0);
        }
        __syncthreads();
    }

    const int mbase = m0 + wr * 64, nbase = n0 + wc * (NTILE / 2);

    if constexpr (EPI == 3) {
        // exp + tq-bias epilogue; tbuf aliases the staging LDS (dead after K-loop)
        u16* tbuf = &lds[0][0];   // needs 64*136 = 8704 u16; available >= 12288
        float cs[NI];
#pragma unroll
        for (int ni = 0; ni < NI; ni++) cs[ni] = 0.f;
#pragma unroll
        for (int h = 0; h < 2; h++) {
#pragma unroll
            for (int mh = 0; mh < 2; mh++) {
                const int mi = h * 2 + mh;
                const int trow = wr * 32 + mh * 16 + fq * 4;
#pragma unroll
                for (int ni = 0; ni < NI; ni++) {
                    const int n = nbase + ni * 16 + fr;
                    const float tqv = bias ? bias[(size_t)bat * N + n] : 0.f;
                    f32x4 v = acc[mi][ni];
#pragma unroll
                    for (int j = 0; j < 4; j++) {
                        float x = __expf((v[j] + tqv) * scale);
                        cs[ni] += x;
                        tbuf[(trow + j) * 136 + wc * 64 + ni * 16 + fr] = f2us(x);
                    }
                }
            }
            __syncthreads();
#pragma unroll
            for (int it = 0; it < 4; it++) {
                const int idx = it * 256 + tid;
                const int row = idx >> 4, ng = idx & 15;
                const int m = m0 + (row >> 5) * 64 + h * 32 + (row & 31);
                u16x8 v8 = *(const u16x8*)&tbuf[row * 136 + ng * 8];
                *(u16x8*)((u16*)Cc + (size_t)bat * cBat + (size_t)m * ldc + n0 + ng * 8) = v8;
            }
            __syncthreads();
        }
        // per-column (n) partial sums over this block's 128 rows (p)
#pragma unroll
        for (int ni = 0; ni < NI; ni++) {
            float s = cs[ni];
            s += __shfl_xor(s, 16, 64);
            s += __shfl_xor(s, 32, 64);
            if (fq == 0) red[wr * 128 + wc * 64 + ni * 16 + fr] = s;
        }
        __syncthreads();
        if (tid < NTILE) {
            float s = red[tid] + red[128 + tid];
            csum[((size_t)bat * gridDim.y + bidy) * ldc + n0 + tid] = s;
        }
        return;
    }

#pragma unroll
    for (int mi = 0; mi < 4; mi++) {
        float esc[4], ead[4];
#pragma unroll
        for (int j = 0; j < 4; j++) {
            int m = mbase + mi * 16 + fq * 4 + j;
            if (EPI == 1) {
                float sc2 = gamma[m] * rsqrtf(var[m] + 1e-5f);
                esc[j] = sc2; ead[j] = beta[m] - mean[m] * sc2;
            } else {
                esc[j] = scale;
                ead[j] = ((EPI == 0 || EPI == 2) && bias) ? bias[m] : 0.f;
            }
        }
#pragma unroll
        for (int ni = 0; ni < NI; ni++) {
            f32x4 v = acc[mi][ni];
            const int n = nbase + ni * 16 + fr;
            if (CT) {
                const int mb = mbase + mi * 16 + fq * 4;
                if constexpr (EPI == 4) {
                    // fp32 float4 store: out[n][mb..mb+3] = v*scale + bias[n] + resid
                    const float bb = bias ? bias[n] : 0.f;
                    float4 rv = *(const float4*)&resid[(size_t)bat * rBat + (size_t)n * ldr + mb];
                    float4 o4;
                    o4.x = v[0] * scale + bb + rv.x;
                    o4.y = v[1] * scale + bb + rv.y;
                    o4.z = v[2] * scale + bb + rv.z;
                    o4.w = v[3] * scale + bb + rv.w;
                    *(float4*)((float*)Cc + (size_t)bat * cBat + (size_t)n * ldc + mb) = o4;
                } else {
                    const long crow = (EPI == 1)
                        ? (long)(((n >> 6) + 1) * 66 + (n & 63) + 1)   // padded pixel (h1p)
                        : (long)n;
                    u16x4 pk;
#pragma unroll
                    for (int j = 0; j < 4; j++) {
                        float x = v[j] * esc[j] + ead[j];
                        if (EPI == 1) x = x > 0.f ? x : 0.1f * x;
                        pk[j] = f2us(x);
                    }
                    *(u16x4*)((u16*)Cc + (size_t)bat * cBat + (size_t)crow * ldc + mb) = pk;
                }
            } else {
#pragma unroll
                for (int j = 0; j < 4; j++) {
                    int m = mbase + mi * 16 + fq * 4 + j;
                    float x = v[j] * esc[j] + ead[j];
                    if (EPI == 1) x = x > 0.f ? x : 0.1f * x;
                    if (EPI == 2) x += resid[(size_t)bat * rBat + (size_t)m * ldr + n];
                    TC* p = Cc + (size_t)bat * cBat + (size_t)m * ldc + n;
                    if constexpr (sizeof(TC) == 2) *(u16*)p = f2us(x); else *(float*)p = x;
                }
            }
        }
    }
}

// ---------------- conv2 3x3 pad1, tap-major implicit GEMM, halo-padded input ----------------
// A = wr [256][2304] (k = tap*256+c) via gload_lds (source-XOR swizzle);
// B = h1p [B][66][66][256] (zero halo -> NO OOB logic) via gload_lds, 64-px tile.
// (r13/r18-proven config: ~58.7 us, FETCH ~30 MB, zero bank conflicts)
__global__ __launch_bounds__(256) void conv3x3_mfma(
    const u16* __restrict__ Wt, const u16* __restrict__ Xp, u16* __restrict__ Y,
    const float* __restrict__ bias)
{
    const int C = 256, P = 4096, K = 2304;
    __shared__ u16 Al[2][128 * 32];
    __shared__ u16 Bl[64 * 64];
    const int bat = blockIdx.z;
    const int m0 = blockIdx.y * 128;
    const int y0 = blockIdx.x;                 // output image row; n0 = y0*64
    const int tid = threadIdx.x;
    const int lane = tid & 63, wid = tid >> 6;
    const int wr = wid >> 1, wc = wid & 1;
    const int fr = lane & 15, fq = lane >> 4;
    const int scA = ((lane & 3) ^ ((lane >> 3) & 3)) * 8;
    const int axs = (fq ^ ((fr >> 1) & 3)) * 8;

    const u16* Ag = Wt + (size_t)(m0 + wid * 32 + (lane >> 2)) * K + scA;
    u16* lA0 = &Al[0][(wid * 32) * 32];
    u16* lA1 = &Al[1][(wid * 32) * 32];
    const u16* Xb = Xp + (size_t)bat * 66 * 66 * 256;

    const int brow = (lane >> 3), bq = lane & 7;

    f32x4 acc[4][2];
#pragma unroll
    for (int i = 0; i < 4; i++)
#pragma unroll
        for (int j = 0; j < 2; j++) acc[i][j] = (f32x4){0.f, 0.f, 0.f, 0.f};

    for (int k0 = 0; k0 < K; k0 += 64) {
        const int tap = k0 >> 8, c0k = k0 & 255;       // 4 steps per tap
        const int dy = tap / 3 - 1, dxv = tap - (tap / 3) * 3 - 1;
        const int syp = y0 + dy + 1;                    // padded y in [0,65]
        gload16(Ag + k0,                       lA0);
        gload16(Ag + k0 + (size_t)16 * K,      lA0 + 16 * 32);
        gload16(Ag + k0 + 32,                  lA1);
        gload16(Ag + k0 + 32 + (size_t)16 * K, lA1 + 16 * 32);
#pragma unroll
        for (int h = 0; h < 2; h++) {
            const int g = wid * 2 + h;
            const int r = g * 8 + brow;
            const int qs = bq ^ (r & 7);
            const u16* src = Xb + ((size_t)syp * 66 + (r + dxv + 1)) * 256 + c0k + qs * 8;
            gload16(src, &Bl[g * 512]);
        }
        __syncthreads();
#pragma unroll
        for (int t = 0; t < 2; t++) {
            b8v a[4], b[2];
#pragma unroll
            for (int mi = 0; mi < 4; mi++) a[mi] = *(const b8v*)&Al[t][(wr * 64 + mi * 16 + fr) * 32 + axs];
#pragma unroll
            for (int ni = 0; ni < 2; ni++) {
                const int row = wc * 32 + ni * 16 + fr;
                const int ch = ((t * 4 + fq) ^ (row & 7)) * 8;
                b[ni] = *(const b8v*)&Bl[row * 64 + ch];
            }
#pragma unroll
            for (int mi = 0; mi < 4; mi++)
#pragma unroll
                for (int ni = 0; ni < 2; ni++)
                    acc[mi][ni] = __builtin_amdgcn_mfma_f32_16x16x32_bf16(a[mi], b[ni], acc[mi][ni], 0, 0, 0);
        }
        __syncthreads();
    }

    const int mbase = m0 + wr * 64, nbase = y0 * 64 + wc * 32;
#pragma unroll
    for (int mi = 0; mi < 4; mi++) {
        const int mb = mbase + mi * 16 + fq * 4;
        float bb[4];
#pragma unroll
        for (int j = 0; j < 4; j++) bb[j] = bias[mb + j];
#pragma unroll
        for (int ni = 0; ni < 2; ni++) {
            const int n = nbase + ni * 16 + fr;
            u16x4 pk;
#pragma unroll
            for (int j = 0; j < 4; j++) pk[j] = f2us(acc[mi][ni][j] + bb[j]);
            *(u16x4*)&Y[(size_t)bat * P * C + (size_t)n * C + mb] = pk;
        }
    }
}

// ---------------- small mid-pipeline kernels ----------------

// tq[b][n] = sum_o bq[o] * Kt[b][n][o]
__global__ __launch_bounds__(256) void tq_dot(const u16* __restrict__ Kt,
                                              const float* __restrict__ bq,
                                              float* __restrict__ tq, int N, int C)
{
    const int n = blockIdx.x * 256 + threadIdx.x, b = blockIdx.y;
    const u16* row = Kt + ((size_t)b * N + n) * C;
    float s = 0.f;
    for (int c = 0; c < C; c += 8) {
        u16x8 v = *(const u16x8*)&row[c];
#pragma unroll
        for (int j = 0; j < 8; j++) s += us2f(v[j]) * bq[c + j];
    }
    tq[(size_t)b * N + n] = s;
}

// fused: sinv[n] = 1/sum(part col n)  (LDS only), then Vt[b][n][:] *= sinv[n]
// grid (N/64, B), 256 threads.
__global__ __launch_bounds__(256) void colsum_scale(const float* __restrict__ part,
                                                    u16* __restrict__ Vt,
                                                    int N, int C, int PC)
{
    __shared__ float si[64];
    const int n0 = blockIdx.x * 64, b = blockIdx.y;
    const int t = threadIdx.x;
    if (t < 64) {
        const float* pc = part + (size_t)b * PC * N + n0 + t;
        float s = 0.f;
        for (int c = 0; c < PC; c++) s += pc[(size_t)c * N];
        si[t] = 1.f / s;
    }
    __syncthreads();
    const int r = t >> 2, q = t & 3;
    const float scv = si[r];
    u16* row = Vt + ((size_t)b * N + n0 + r) * C + q * 64;
#pragma unroll
    for (int j = 0; j < 8; j++) {
        u16x8 v = *(u16x8*)&row[j * 8];
#pragma unroll
        for (int l = 0; l < 8; l++) v[l] = f2us(us2f(v[l]) * scv);
        *(u16x8*)&row[j * 8] = v;
    }
}

// ---------------- launch ----------------
// ws map (88 MiB cap) — identical to round 18/19 (proven PASS):
//   [0,128K) WqT (dead pre-E)  |  [0,64) E (E-gemm .. h1-gemm)  |  [0,16) h2T (post h1)
//   [64,80) xT (dead post-E)
//   [80,84) Kt (dead post-KW/tq) -> VV (VV-gemm .. h1-gemm)
//   [84,88) Vt (dead post-VV)
//   [17,18.2) c2w_b, [19,19.2) c3w_b  (written after h1-gemm, E dead)
// d_out scratch (all dead before final out-GEMM):
//   [0,1M) csum part | [2,6M) KWt | [6M,+32K) tq
//   [8M,+128K) c1w_b | [14M, 31.02M) h1p padded [B][66][66][256]

extern "C" void kernel_launch(void* const* d_in, const int* in_sizes, int n_in,
                              void* d_out, int out_size, void* d_ws, size_t ws_size,
                              hipStream_t stream)
{
    const float* graph = (const float*)d_in[0];   // [8,1024,32]
    const float* image = (const float*)d_in[1];   // [8,256,64,64]
    const float* Wq  = (const float*)d_in[2];
    const float* bq  = (const float*)d_in[3];
    const float* Wk  = (const float*)d_in[4];
    const float* bk  = (const float*)d_in[5];
    const float* Wv  = (const float*)d_in[6];
    const float* bv  = (const float*)d_in[7];
    const float* c1w = (const float*)d_in[8];
    const float* gam = (const float*)d_in[9];
    const float* bet = (const float*)d_in[10];
    const float* mea = (const float*)d_in[11];
    const float* var = (const float*)d_in[12];
    const float* c2w = (const float*)d_in[13];
    const float* c2b = (const float*)d_in[14];
    const float* c3w = (const float*)d_in[15];
    const float* c3b = (const float*)d_in[16];
    float* out = (float*)d_out;

    const int B = 8, C = 256, P = 4096, N = 1024, G = 32;
    const size_t MiB = 1024 * 1024, KiB = 1024;
    char* ws = (char*)d_ws;
    char* dob = (char*)d_out;
    // ws
    u16* WqT  = (u16*)(ws);                       // [0,128K), dead pre-E
    u16* E    = (u16*)(ws);                       // [0,64)
    u16* xT   = (u16*)(ws + 64 * MiB);            // [64,80)
    u16* Kt   = (u16*)(ws + 80 * MiB);            // [80,84)
    u16* VV   = (u16*)(ws + 80 * MiB);            // reuse after Kt dead
    u16* Vt   = (u16*)(ws + 84 * MiB);            // [84,88)
    u16* h2T  = (u16*)(ws);                       // [0,16) post h1-gemm
    u16* c2w_b = (u16*)(ws + 17 * MiB);
    u16* c3w_b = (u16*)(ws + 19 * MiB);
    // d_out scratch
    float* part = (float*)(dob);                  // 1 MiB
    u16* KWt   = (u16*)(dob + 2 * MiB);           // 4 MiB [B][N][C]
    float* tqb = (float*)(dob + 6 * MiB);         // 32 KiB
    u16* c1w_b = (u16*)(dob + 8 * MiB);           // 128 KiB
    u16* h1p   = (u16*)(dob + 14 * MiB);          // 17.02 MiB [B][66][66][256]

    // prep
    transpose_cast_x<<<dim3(P / 64, C / 64, B), 256, 0, stream>>>(image, xT, C, P);
    transpose_cast_x<<<dim3(4, 4, 1), 256, 0, stream>>>(Wq, WqT, 256, 256);
    cast_f2b4<<<64, 256, 0, stream>>>(c1w, c1w_b, 16384);
    // Kt[b][n][o] = graph.Wk + bk ; Vt[b][n][o] = graph.Wv + bv   (one launch)
    kv_proj<<<dim3(C / 64, N / 64, 2 * B), 256, 0, stream>>>(
        graph, Wk, bk, Wv, bv, (bf16*)Kt, (bf16*)Vt, N, C, G);
    // KWt[b][n][c] = sum_o Kt[n][o] * Wq[o][c]   (A=Kt, Bt=WqT)
    gemm_mfma<0, false, u16, 64><<<dim3(C / 64, N / 128, B), 256, 0, stream>>>(
        Kt, WqT, KWt, N, C, C, C, C, C,
        (long)N * C, 0, (long)N * C, 1.f, nullptr,
        nullptr, nullptr, nullptr, nullptr, nullptr, 0, 0, nullptr);
    // tq[b][n] = sum_o bq[o] * Kt[b][n][o]
    tq_dot<<<dim3(N / 256, B), 256, 0, stream>>>(Kt, bq, tqb, N, C);
    // E[b][p][n] = exp((xT.KWt + tq[n]) / 16); column partials -> part (in d_out)
    gemm_mfma<3, false, u16, 128><<<dim3(N / 128, P / 128, B), 256, 0, stream>>>(
        xT, KWt, E, P, N, C, C, C, N,
        (long)P * C, (long)N * C, (long)P * N, 0.0625f, tqb,
        nullptr, nullptr, nullptr, nullptr, nullptr, 0, 0, part);
    // softmax denominator folded into Vt rows (one launch; PC = P/128 = E-gemm gridDim.y)
    colsum_scale<<<dim3(N / 64, B), 256, 0, stream>>>(part, Vt, N, C, P / 128);
    // VV[b][o][n] = sum_c c1w[o][c] * Vt'[n][c]
    gemm_mfma<0, false, u16, 64><<<dim3(N / 64, C / 128, B), 256, 0, stream>>>(
        c1w_b, Vt, VV, C, N, C, C, C, N,
        0, (long)N * C, (long)C * N, 1.f, nullptr,
        nullptr, nullptr, nullptr, nullptr, nullptr, 0, 0, nullptr);
    // h1p = LeakyReLU(BN(VV . E^T))  -- padded CT store [66][66][256]
    gemm_mfma<1, true, u16, 64><<<dim3(P / 64, C / 128, B), 256, 0, stream>>>(
        VV, E, h1p, C, P, N, N, N, C,
        (long)C * N, (long)P * N, (long)66 * 66 * C, 1.f, nullptr,
        gam, bet, mea, var, nullptr, 0, 0, nullptr);
    // fused post-h1 prep: repack c2w + cast c3w (E dead now) + zero h1p halo
    prep2<<<2628, 256, 0, stream>>>(c2w, c2w_b, c3w, c3w_b, h1p);
    // h2T[b][p][c] = conv2 3x3(h1p) + c2b   (64-px tile, proven config)
    conv3x3_mfma<<<dim3(P / 64, C / 128, B), 256, 0, stream>>>(c2w_b, h1p, h2T, c2b);
    // out[b][o][p] = image + conv3(h2) + c3b   (CT orientation, float4 I/O)
    gemm_mfma<4, true, float, 64><<<dim3(C / 64, P / 128, B), 256, 0, stream>>>(
        h2T, c3w_b, out, P, C, C, C, C, P,
        (long)P * C, 0, (long)C * P, 1.f, c3b,
        nullptr, nullptr, nullptr, nullptr, image, (long)C * P, P, nullptr);
}

// Round 21
// 208.914 us; speedup vs baseline: 1.0319x; 1.0319x over previous
//
#include <hip/hip_runtime.h>
#include <hip/hip_bf16.h>

typedef __hip_bfloat16 bf16;
typedef unsigned short u16;
typedef __attribute__((ext_vector_type(8))) short  b8v;    // 8 bf16 bits (4 VGPR) MFMA operand
typedef __attribute__((ext_vector_type(8))) unsigned short u16x8;
typedef __attribute__((ext_vector_type(4))) unsigned short u16x4;
typedef __attribute__((ext_vector_type(4))) float f32x4;

static __device__ __forceinline__ float us2f(u16 s) {
    unsigned int u = ((unsigned int)s) << 16;
    return __builtin_bit_cast(float, u);
}
static __device__ __forceinline__ u16 f2us(float x) {
    union { bf16 h; u16 s; } v; v.h = __float2bfloat16(x); return v.s;
}
static __device__ __forceinline__ float b2f(bf16 x) { return __bfloat162float(x); }
static __device__ __forceinline__ bf16 f2b(float x) { return __float2bfloat16(x); }

// async global->LDS, 16 bytes/lane. Dest is wave-uniform base + lane*16;
// global source IS per-lane (m173 pre-swizzled-source pattern).
static __device__ __forceinline__ void gload16(const u16* g, u16* l) {
    __builtin_amdgcn_global_load_lds(
        (const __attribute__((address_space(1))) unsigned int*)g,
        (__attribute__((address_space(3))) unsigned int*)l,
        16, 0, 0);
}

// ---------------- prep kernels ----------------

__global__ __launch_bounds__(256) void cast_f2b4(const float* __restrict__ src,
                                                 u16* __restrict__ dst, int n4)
{
    int i = blockIdx.x * 256 + threadIdx.x;
    if (i < n4) {
        float4 v = ((const float4*)src)[i];
        u16x4 o = { f2us(v.x), f2us(v.y), f2us(v.z), f2us(v.w) };
        ((u16x4*)dst)[i] = o;
    }
}

// src[M][P] f32 -> dst[P][M] bf16, 64x64 LDS tiles (also used for Wq transpose)
__global__ __launch_bounds__(256) void transpose_cast_x(const float* __restrict__ x,
                                                        u16* __restrict__ xT, int C, int P)
{
    __shared__ u16 t[64][72];
    const int b = blockIdx.z, c0 = blockIdx.y * 64, p0 = blockIdx.x * 64;
    const int tid = threadIdx.x;
    const int r = tid >> 2, q = tid & 3;
    const float* src = x + ((size_t)b * C + c0 + r) * P + p0 + q * 16;
#pragma unroll
    for (int i = 0; i < 16; i++) t[q * 16 + i][r] = f2us(src[i]);
    __syncthreads();
    u16* dst = xT + ((size_t)b * P + p0 + r) * C + c0 + q * 16;
    *(u16x8*)dst       = *(u16x8*)&t[r][q * 16];
    *(u16x8*)(dst + 8) = *(u16x8*)&t[r][q * 16 + 8];
}

// fused post-h1 prep: conv2 weight repack (blocks 0..2303), c3w cast (2304..2367),
// h1p halo zero (2368..2627). All independent, all needed before conv/out.
__global__ __launch_bounds__(256) void prep2(const float* __restrict__ c2w,
                                             u16* __restrict__ c2w_b,
                                             const float* __restrict__ c3w,
                                             u16* __restrict__ c3w_b,
                                             u16* __restrict__ h1p)
{
    const int blk = blockIdx.x;
    if (blk < 2304) {
        int idx = blk * 256 + threadIdx.x;          // 256*2304
        int o = idx / 2304, k = idx - o * 2304;
        int tap = k >> 8, c = k & 255;
        c2w_b[idx] = f2us(c2w[(o * 256 + c) * 9 + tap]);
    } else if (blk < 2368) {
        int i = (blk - 2304) * 256 + threadIdx.x;   // 16384 float4
        float4 v = ((const float4*)c3w)[i];
        u16x4 o = { f2us(v.x), f2us(v.y), f2us(v.z), f2us(v.w) };
        ((u16x4*)c3w_b)[i] = o;
    } else {
        int i = (blk - 2368) * 256 + threadIdx.x;   // 8*260*32
        const int ch8 = i & 31; i >>= 5;
        const int hp = i % 260;
        const int b = i / 260;
        int py, px;
        if (hp < 66)       { py = 0;  px = hp; }
        else if (hp < 132) { py = 65; px = hp - 66; }
        else if (hp < 196) { py = hp - 132 + 1; px = 0; }
        else               { py = hp - 196 + 1; px = 65; }
        u16x8 z = {0, 0, 0, 0, 0, 0, 0, 0};
        *(u16x8*)&h1p[(((size_t)b * 66 + py) * 66 + px) * 256 + ch8 * 8] = z;
    }
}

// ---------------- fused K/V projection (K=32 VALU GEMM, one launch) ----------------
// z = b + 8*isV: out[b][n][c] = sum_g graph[b][n][g] * W[c][g] + bias[c]
__global__ __launch_bounds__(256) void kv_proj(
    const float* __restrict__ graph,
    const float* __restrict__ Wk, const float* __restrict__ bk,
    const float* __restrict__ Wv, const float* __restrict__ bv,
    bf16* __restrict__ Kt, bf16* __restrict__ Vt, int N, int C, int G)
{
    const int z = blockIdx.z;
    const int b = z & 7;
    const bool isv = (z >> 3) != 0;
    const float* W    = isv ? Wv : Wk;
    const float* bias = isv ? bv : bk;
    bf16* Out         = isv ? Vt : Kt;
    __shared__ float As[16][65];
    __shared__ float Bs[16][65];
    const float* Ab = graph + (long)b * N * G;
    const int m0 = blockIdx.y * 64, n0 = blockIdx.x * 64;
    const int tid = threadIdx.x;
    const int tx = tid & 15, ty = tid >> 4;
    float acc[4][4] = {};

    for (int k0 = 0; k0 < G; k0 += 16) {
#pragma unroll
        for (int i = 0; i < 4; i++) {
            int idx = tid + i * 256; int kk = idx & 15, mm = idx >> 4;
            As[kk][mm] = Ab[(long)(m0 + mm) * G + k0 + kk];
        }
#pragma unroll
        for (int i = 0; i < 4; i++) {
            int idx = tid + i * 256; int kk = idx & 15, nn = idx >> 4;
            Bs[kk][nn] = W[(long)(n0 + nn) * G + k0 + kk];
        }
        __syncthreads();
#pragma unroll
        for (int kk = 0; kk < 16; kk++) {
            float a[4], bb[4];
#pragma unroll
            for (int i = 0; i < 4; i++) a[i]  = As[kk][ty * 4 + i];
#pragma unroll
            for (int j = 0; j < 4; j++) bb[j] = Bs[kk][tx * 4 + j];
#pragma unroll
            for (int i = 0; i < 4; i++)
#pragma unroll
                for (int j = 0; j < 4; j++) acc[i][j] += a[i] * bb[j];
        }
        __syncthreads();
    }
#pragma unroll
    for (int i = 0; i < 4; i++) {
        int m = m0 + ty * 4 + i;
#pragma unroll
        for (int j = 0; j < 4; j++) {
            int n = n0 + tx * 4 + j;
            Out[(long)b * N * C + (long)m * C + n] = f2b(acc[i][j] + bias[n]);
        }
    }
}

// ---------------- MFMA GEMM (m97 + T2 XOR swizzle + T1 XCD swizzle + BK=64) ----------------
// C[m][n] = epi( scale * sum_k A[m][k] * Bt[n][k] ); A,Bt k-contiguous bf16-bits.
// BK=64 double-plane staging: per iteration, 8 gload_lds fill two 32-k planes,
// then ONE barrier pair covers 2 MFMA sub-steps (halves barrier-drain count).
// LDS rows 32 u16; chunk c of row r stored at c ^ ((r>>1)&3) via pre-swizzled
// per-lane GLOBAL source (rule 21). Reads 2-way max.
// EPI: 0 scale+bias[m]; 1 BN+LeakyReLU (CT: padded [66][66][C] store);
//      3 exp((acc + bias[bat*N+n]) * scale), LDS-transposed u16x8 stores
//        (tbuf aliases the staging LDS, dead after K-loop), col partials -> csum;
//      4 (CT) fp32 float4 store: v*scale + bias[n] + resid[n][mb..mb+3]
template<int EPI, bool CT, typename TC, int NTILE>
__global__ __launch_bounds__(256) void gemm_mfma(
    const u16* __restrict__ A, const u16* __restrict__ Bt, TC* __restrict__ Cc,
    int M, int N, int K, int lda, int ldb, int ldc,
    long aBat, long bBat, long cBat,
    float scale, const float* __restrict__ bias,
    const float* __restrict__ gamma, const float* __restrict__ beta,
    const float* __restrict__ mean,  const float* __restrict__ var,
    const float* __restrict__ resid, long rBat, int ldr,
    float* __restrict__ csum)
{
    constexpr int NI = NTILE / 32;          // B fragments per wave
    constexpr int AW = 128 * 32;            // A plane size in u16
    constexpr int BW = NTILE * 32;          // B plane size in u16
    __shared__ u16 lds[2][AW + BW];         // [plane][A | B]
    __shared__ float red[(EPI == 3) ? 256 : 1];
    const int bat = blockIdx.z;
    // T1 XCD swizzle (bijective: gx*gy % 8 == 0 at every call site)
    const int nxy = gridDim.x * gridDim.y;
    const int fid = blockIdx.y * gridDim.x + blockIdx.x;
    const int swzid = (fid & 7) * (nxy >> 3) + (fid >> 3);
    const int bidx = swzid % gridDim.x, bidy = swzid / gridDim.x;
    const int m0 = bidy * 128, n0 = bidx * NTILE;
    const int tid = threadIdx.x;
    const int lane = tid & 63, wid = tid >> 6;
    const int wr = wid >> 1, wc = wid & 1;
    const int fr = lane & 15, fq = lane >> 4;
    const int sc = ((lane & 3) ^ ((lane >> 3) & 3)) * 8;   // pre-swizzled source chunk
    const int axs = (fq ^ ((fr >> 1) & 3)) * 8;            // swizzled read chunk

    const u16* gA = A  + (size_t)bat * aBat + (size_t)(m0 + wid * 32 + (lane >> 2)) * lda + sc;
    const u16* gB = Bt + (size_t)bat * bBat + (size_t)(n0 + wid * (NTILE / 4) + (lane >> 2)) * ldb + sc;
    const int aoff = (wid * 32) * 32;
    const int boff = AW + (wid * (NTILE / 4)) * 32;
    const size_t a16 = (size_t)16 * lda, b16 = (size_t)16 * ldb;

    f32x4 acc[4][NI];
#pragma unroll
    for (int i = 0; i < 4; i++)
#pragma unroll
        for (int j = 0; j < NI; j++) acc[i][j] = (f32x4){0.f, 0.f, 0.f, 0.f};

    for (int k0 = 0; k0 < K; k0 += 64) {
        gload16(gA + k0,            &lds[0][aoff]);
        gload16(gA + k0 + a16,      &lds[0][aoff + 16 * 32]);
        gload16(gA + k0 + 32,       &lds[1][aoff]);
        gload16(gA + k0 + 32 + a16, &lds[1][aoff + 16 * 32]);
        gload16(gB + k0,            &lds[0][boff]);
        if constexpr (NTILE == 128) gload16(gB + k0 + b16, &lds[0][boff + 16 * 32]);
        gload16(gB + k0 + 32,       &lds[1][boff]);
        if constexpr (NTILE == 128) gload16(gB + k0 + 32 + b16, &lds[1][boff + 16 * 32]);
        __syncthreads();
#pragma unroll
        for (int t = 0; t < 2; t++) {
            b8v a[4], b[NI];
#pragma unroll
            for (int mi = 0; mi < 4; mi++)
                a[mi] = *(const b8v*)&lds[t][(wr * 64 + mi * 16 + fr) * 32 + axs];
#pragma unroll
            for (int ni = 0; ni < NI; ni++)
                b[ni] = *(const b8v*)&lds[t][AW + (wc * (NTILE / 2) + ni * 16 + fr) * 32 + axs];
#pragma unroll
            for (int mi = 0; mi < 4; mi++)
#pragma unroll
                for (int ni = 0; ni < NI; ni++)
                    acc[mi][ni] = __builtin_amdgcn_mfma_f32_16x16x32_bf16(a[mi], b[ni], acc[mi][ni], 0, 0, 0);
        }
        __syncthreads();
    }

    const int mbase = m0 + wr * 64, nbase = n0 + wc * (NTILE / 2);

    if constexpr (EPI == 3) {
        // exp + tq-bias epilogue; tbuf aliases the staging LDS (dead after K-loop)
        u16* tbuf = &lds[0][0];   // needs 64*136 = 8704 u16; available >= 12288
        float cs[NI];
#pragma unroll
        for (int ni = 0; ni < NI; ni++) cs[ni] = 0.f;
#pragma unroll
        for (int h = 0; h < 2; h++) {
#pragma unroll
            for (int mh = 0; mh < 2; mh++) {
                const int mi = h * 2 + mh;
                const int trow = wr * 32 + mh * 16 + fq * 4;
#pragma unroll
                for (int ni = 0; ni < NI; ni++) {
                    const int n = nbase + ni * 16 + fr;
                    const float tqv = bias ? bias[(size_t)bat * N + n] : 0.f;
                    f32x4 v = acc[mi][ni];
#pragma unroll
                    for (int j = 0; j < 4; j++) {
                        float x = __expf((v[j] + tqv) * scale);
                        cs[ni] += x;
                        tbuf[(trow + j) * 136 + wc * 64 + ni * 16 + fr] = f2us(x);
                    }
                }
            }
            __syncthreads();
#pragma unroll
            for (int it = 0; it < 4; it++) {
                const int idx = it * 256 + tid;
                const int row = idx >> 4, ng = idx & 15;
                const int m = m0 + (row >> 5) * 64 + h * 32 + (row & 31);
                u16x8 v8 = *(const u16x8*)&tbuf[row * 136 + ng * 8];
                *(u16x8*)((u16*)Cc + (size_t)bat * cBat + (size_t)m * ldc + n0 + ng * 8) = v8;
            }
            __syncthreads();
        }
        // per-column (n) partial sums over this block's 128 rows (p)
#pragma unroll
        for (int ni = 0; ni < NI; ni++) {
            float s = cs[ni];
            s += __shfl_xor(s, 16, 64);
            s += __shfl_xor(s, 32, 64);
            if (fq == 0) red[wr * 128 + wc * 64 + ni * 16 + fr] = s;
        }
        __syncthreads();
        if (tid < NTILE) {
            float s = red[tid] + red[128 + tid];
            csum[((size_t)bat * gridDim.y + bidy) * ldc + n0 + tid] = s;
        }
        return;
    }

#pragma unroll
    for (int mi = 0; mi < 4; mi++) {
        float esc[4], ead[4];
#pragma unroll
        for (int j = 0; j < 4; j++) {
            int m = mbase + mi * 16 + fq * 4 + j;
            if (EPI == 1) {
                float sc2 = gamma[m] * rsqrtf(var[m] + 1e-5f);
                esc[j] = sc2; ead[j] = beta[m] - mean[m] * sc2;
            } else {
                esc[j] = scale;
                ead[j] = ((EPI == 0 || EPI == 2) && bias) ? bias[m] : 0.f;
            }
        }
#pragma unroll
        for (int ni = 0; ni < NI; ni++) {
            f32x4 v = acc[mi][ni];
            const int n = nbase + ni * 16 + fr;
            if (CT) {
                const int mb = mbase + mi * 16 + fq * 4;
                if constexpr (EPI == 4) {
                    // fp32 float4 store: out[n][mb..mb+3] = v*scale + bias[n] + resid
                    const float bb = bias ? bias[n] : 0.f;
                    float4 rv = *(const float4*)&resid[(size_t)bat * rBat + (size_t)n * ldr + mb];
                    float4 o4;
                    o4.x = v[0] * scale + bb + rv.x;
                    o4.y = v[1] * scale + bb + rv.y;
                    o4.z = v[2] * scale + bb + rv.z;
                    o4.w = v[3] * scale + bb + rv.w;
                    *(float4*)((float*)Cc + (size_t)bat * cBat + (size_t)n * ldc + mb) = o4;
                } else {
                    const long crow = (EPI == 1)
                        ? (long)(((n >> 6) + 1) * 66 + (n & 63) + 1)   // padded pixel (h1p)
                        : (long)n;
                    u16x4 pk;
#pragma unroll
                    for (int j = 0; j < 4; j++) {
                        float x = v[j] * esc[j] + ead[j];
                        if (EPI == 1) x = x > 0.f ? x : 0.1f * x;
                        pk[j] = f2us(x);
                    }
                    *(u16x4*)((u16*)Cc + (size_t)bat * cBat + (size_t)crow * ldc + mb) = pk;
                }
            } else {
#pragma unroll
                for (int j = 0; j < 4; j++) {
                    int m = mbase + mi * 16 + fq * 4 + j;
                    float x = v[j] * esc[j] + ead[j];
                    if (EPI == 1) x = x > 0.f ? x : 0.1f * x;
                    if (EPI == 2) x += resid[(size_t)bat * rBat + (size_t)m * ldr + n];
                    TC* p = Cc + (size_t)bat * cBat + (size_t)m * ldc + n;
                    if constexpr (sizeof(TC) == 2) *(u16*)p = f2us(x); else *(float*)p = x;
                }
            }
        }
    }
}

// ---------------- conv2 3x3 pad1, tap-major implicit GEMM, halo-padded input ----------------
// A = wr [256][2304] (k = tap*256+c) via gload_lds (source-XOR swizzle);
// B = h1p [B][66][66][256] (zero halo -> NO OOB logic) via gload_lds, 64-px tile.
// (r13/r18-proven config: ~58.7 us, FETCH ~30 MB, zero bank conflicts)
__global__ __launch_bounds__(256) void conv3x3_mfma(
    const u16* __restrict__ Wt, const u16* __restrict__ Xp, u16* __restrict__ Y,
    const float* __restrict__ bias)
{
    const int C = 256, P = 4096, K = 2304;
    __shared__ u16 Al[2][128 * 32];
    __shared__ u16 Bl[64 * 64];
    const int bat = blockIdx.z;
    const int m0 = blockIdx.y * 128;
    const int y0 = blockIdx.x;                 // output image row; n0 = y0*64
    const int tid = threadIdx.x;
    const int lane = tid & 63, wid = tid >> 6;
    const int wr = wid >> 1, wc = wid & 1;
    const int fr = lane & 15, fq = lane >> 4;
    const int scA = ((lane & 3) ^ ((lane >> 3) & 3)) * 8;
    const int axs = (fq ^ ((fr >> 1) & 3)) * 8;

    const u16* Ag = Wt + (size_t)(m0 + wid * 32 + (lane >> 2)) * K + scA;
    u16* lA0 = &Al[0][(wid * 32) * 32];
    u16* lA1 = &Al[1][(wid * 32) * 32];
    const u16* Xb = Xp + (size_t)bat * 66 * 66 * 256;

    const int brow = (lane >> 3), bq = lane & 7;

    f32x4 acc[4][2];
#pragma unroll
    for (int i = 0; i < 4; i++)
#pragma unroll
        for (int j = 0; j < 2; j++) acc[i][j] = (f32x4){0.f, 0.f, 0.f, 0.f};

    for (int k0 = 0; k0 < K; k0 += 64) {
        const int tap = k0 >> 8, c0k = k0 & 255;       // 4 steps per tap
        const int dy = tap / 3 - 1, dxv = tap - (tap / 3) * 3 - 1;
        const int syp = y0 + dy + 1;                    // padded y in [0,65]
        gload16(Ag + k0,                       lA0);
        gload16(Ag + k0 + (size_t)16 * K,      lA0 + 16 * 32);
        gload16(Ag + k0 + 32,                  lA1);
        gload16(Ag + k0 + 32 + (size_t)16 * K, lA1 + 16 * 32);
#pragma unroll
        for (int h = 0; h < 2; h++) {
            const int g = wid * 2 + h;
            const int r = g * 8 + brow;
            const int qs = bq ^ (r & 7);
            const u16* src = Xb + ((size_t)syp * 66 + (r + dxv + 1)) * 256 + c0k + qs * 8;
            gload16(src, &Bl[g * 512]);
        }
        __syncthreads();
#pragma unroll
        for (int t = 0; t < 2; t++) {
            b8v a[4], b[2];
#pragma unroll
            for (int mi = 0; mi < 4; mi++) a[mi] = *(const b8v*)&Al[t][(wr * 64 + mi * 16 + fr) * 32 + axs];
#pragma unroll
            for (int ni = 0; ni < 2; ni++) {
                const int row = wc * 32 + ni * 16 + fr;
                const int ch = ((t * 4 + fq) ^ (row & 7)) * 8;
                b[ni] = *(const b8v*)&Bl[row * 64 + ch];
            }
#pragma unroll
            for (int mi = 0; mi < 4; mi++)
#pragma unroll
                for (int ni = 0; ni < 2; ni++)
                    acc[mi][ni] = __builtin_amdgcn_mfma_f32_16x16x32_bf16(a[mi], b[ni], acc[mi][ni], 0, 0, 0);
        }
        __syncthreads();
    }

    const int mbase = m0 + wr * 64, nbase = y0 * 64 + wc * 32;
#pragma unroll
    for (int mi = 0; mi < 4; mi++) {
        const int mb = mbase + mi * 16 + fq * 4;
        float bb[4];
#pragma unroll
        for (int j = 0; j < 4; j++) bb[j] = bias[mb + j];
#pragma unroll
        for (int ni = 0; ni < 2; ni++) {
            const int n = nbase + ni * 16 + fr;
            u16x4 pk;
#pragma unroll
            for (int j = 0; j < 4; j++) pk[j] = f2us(acc[mi][ni][j] + bb[j]);
            *(u16x4*)&Y[(size_t)bat * P * C + (size_t)n * C + mb] = pk;
        }
    }
}

// ---------------- small mid-pipeline kernels ----------------

// tq[b][n] = sum_o bq[o] * Kt[b][n][o]
__global__ __launch_bounds__(256) void tq_dot(const u16* __restrict__ Kt,
                                              const float* __restrict__ bq,
                                              float* __restrict__ tq, int N, int C)
{
    const int n = blockIdx.x * 256 + threadIdx.x, b = blockIdx.y;
    const u16* row = Kt + ((size_t)b * N + n) * C;
    float s = 0.f;
    for (int c = 0; c < C; c += 8) {
        u16x8 v = *(const u16x8*)&row[c];
#pragma unroll
        for (int j = 0; j < 8; j++) s += us2f(v[j]) * bq[c + j];
    }
    tq[(size_t)b * N + n] = s;
}

// fused: sinv[n] = 1/sum(part col n)  (LDS only), then Vt[b][n][:] *= sinv[n]
// grid (N/64, B), 256 threads.
__global__ __launch_bounds__(256) void colsum_scale(const float* __restrict__ part,
                                                    u16* __restrict__ Vt,
                                                    int N, int C, int PC)
{
    __shared__ float si[64];
    const int n0 = blockIdx.x * 64, b = blockIdx.y;
    const int t = threadIdx.x;
    if (t < 64) {
        const float* pc = part + (size_t)b * PC * N + n0 + t;
        float s = 0.f;
        for (int c = 0; c < PC; c++) s += pc[(size_t)c * N];
        si[t] = 1.f / s;
    }
    __syncthreads();
    const int r = t >> 2, q = t & 3;
    const float scv = si[r];
    u16* row = Vt + ((size_t)b * N + n0 + r) * C + q * 64;
#pragma unroll
    for (int j = 0; j < 8; j++) {
        u16x8 v = *(u16x8*)&row[j * 8];
#pragma unroll
        for (int l = 0; l < 8; l++) v[l] = f2us(us2f(v[l]) * scv);
        *(u16x8*)&row[j * 8] = v;
    }
}

// ---------------- launch ----------------
// ws map (88 MiB cap) — identical to round 18/19 (proven PASS):
//   [0,128K) WqT (dead pre-E)  |  [0,64) E (E-gemm .. h1-gemm)  |  [0,16) h2T (post h1)
//   [64,80) xT (dead post-E)
//   [80,84) Kt (dead post-KW/tq) -> VV (VV-gemm .. h1-gemm)
//   [84,88) Vt (dead post-VV)
//   [17,18.2) c2w_b, [19,19.2) c3w_b  (written after h1-gemm, E dead)
// d_out scratch (all dead before final out-GEMM):
//   [0,1M) csum part | [2,6M) KWt | [6M,+32K) tq
//   [8M,+128K) c1w_b | [14M, 31.02M) h1p padded [B][66][66][256]

extern "C" void kernel_launch(void* const* d_in, const int* in_sizes, int n_in,
                              void* d_out, int out_size, void* d_ws, size_t ws_size,
                              hipStream_t stream)
{
    const float* graph = (const float*)d_in[0];   // [8,1024,32]
    const float* image = (const float*)d_in[1];   // [8,256,64,64]
    const float* Wq  = (const float*)d_in[2];
    const float* bq  = (const float*)d_in[3];
    const float* Wk  = (const float*)d_in[4];
    const float* bk  = (const float*)d_in[5];
    const float* Wv  = (const float*)d_in[6];
    const float* bv  = (const float*)d_in[7];
    const float* c1w = (const float*)d_in[8];
    const float* gam = (const float*)d_in[9];
    const float* bet = (const float*)d_in[10];
    const float* mea = (const float*)d_in[11];
    const float* var = (const float*)d_in[12];
    const float* c2w = (const float*)d_in[13];
    const float* c2b = (const float*)d_in[14];
    const float* c3w = (const float*)d_in[15];
    const float* c3b = (const float*)d_in[16];
    float* out = (float*)d_out;

    const int B = 8, C = 256, P = 4096, N = 1024, G = 32;
    const size_t MiB = 1024 * 1024, KiB = 1024;
    char* ws = (char*)d_ws;
    char* dob = (char*)d_out;
    // ws
    u16* WqT  = (u16*)(ws);                       // [0,128K), dead pre-E
    u16* E    = (u16*)(ws);                       // [0,64)
    u16* xT   = (u16*)(ws + 64 * MiB);            // [64,80)
    u16* Kt   = (u16*)(ws + 80 * MiB);            // [80,84)
    u16* VV   = (u16*)(ws + 80 * MiB);            // reuse after Kt dead
    u16* Vt   = (u16*)(ws + 84 * MiB);            // [84,88)
    u16* h2T  = (u16*)(ws);                       // [0,16) post h1-gemm
    u16* c2w_b = (u16*)(ws + 17 * MiB);
    u16* c3w_b = (u16*)(ws + 19 * MiB);
    // d_out scratch
    float* part = (float*)(dob);                  // 1 MiB
    u16* KWt   = (u16*)(dob + 2 * MiB);           // 4 MiB [B][N][C]
    float* tqb = (float*)(dob + 6 * MiB);         // 32 KiB
    u16* c1w_b = (u16*)(dob + 8 * MiB);           // 128 KiB
    u16* h1p   = (u16*)(dob + 14 * MiB);          // 17.02 MiB [B][66][66][256]

    // prep
    transpose_cast_x<<<dim3(P / 64, C / 64, B), 256, 0, stream>>>(image, xT, C, P);
    transpose_cast_x<<<dim3(4, 4, 1), 256, 0, stream>>>(Wq, WqT, 256, 256);
    cast_f2b4<<<64, 256, 0, stream>>>(c1w, c1w_b, 16384);
    // Kt[b][n][o] = graph.Wk + bk ; Vt[b][n][o] = graph.Wv + bv   (one launch)
    kv_proj<<<dim3(C / 64, N / 64, 2 * B), 256, 0, stream>>>(
        graph, Wk, bk, Wv, bv, (bf16*)Kt, (bf16*)Vt, N, C, G);
    // KWt[b][n][c] = sum_o Kt[n][o] * Wq[o][c]   (A=Kt, Bt=WqT)
    gemm_mfma<0, false, u16, 64><<<dim3(C / 64, N / 128, B), 256, 0, stream>>>(
        Kt, WqT, KWt, N, C, C, C, C, C,
        (long)N * C, 0, (long)N * C, 1.f, nullptr,
        nullptr, nullptr, nullptr, nullptr, nullptr, 0, 0, nullptr);
    // tq[b][n] = sum_o bq[o] * Kt[b][n][o]
    tq_dot<<<dim3(N / 256, B), 256, 0, stream>>>(Kt, bq, tqb, N, C);
    // E[b][p][n] = exp((xT.KWt + tq[n]) / 16); column partials -> part (in d_out)
    gemm_mfma<3, false, u16, 128><<<dim3(N / 128, P / 128, B), 256, 0, stream>>>(
        xT, KWt, E, P, N, C, C, C, N,
        (long)P * C, (long)N * C, (long)P * N, 0.0625f, tqb,
        nullptr, nullptr, nullptr, nullptr, nullptr, 0, 0, part);
    // softmax denominator folded into Vt rows (one launch; PC = P/128 = E-gemm gridDim.y)
    colsum_scale<<<dim3(N / 64, B), 256, 0, stream>>>(part, Vt, N, C, P / 128);
    // VV[b][o][n] = sum_c c1w[o][c] * Vt'[n][c]
    gemm_mfma<0, false, u16, 64><<<dim3(N / 64, C / 128, B), 256, 0, stream>>>(
        c1w_b, Vt, VV, C, N, C, C, C, N,
        0, (long)N * C, (long)C * N, 1.f, nullptr,
        nullptr, nullptr, nullptr, nullptr, nullptr, 0, 0, nullptr);
    // h1p = LeakyReLU(BN(VV . E^T))  -- padded CT store [66][66][256]
    gemm_mfma<1, true, u16, 64><<<dim3(P / 64, C / 128, B), 256, 0, stream>>>(
        VV, E, h1p, C, P, N, N, N, C,
        (long)C * N, (long)P * N, (long)66 * 66 * C, 1.f, nullptr,
        gam, bet, mea, var, nullptr, 0, 0, nullptr);
    // fused post-h1 prep: repack c2w + cast c3w (E dead now) + zero h1p halo
    prep2<<<2628, 256, 0, stream>>>(c2w, c2w_b, c3w, c3w_b, h1p);
    // h2T[b][p][c] = conv2 3x3(h1p) + c2b   (64-px tile, proven config)
    conv3x3_mfma<<<dim3(P / 64, C / 128, B), 256, 0, stream>>>(c2w_b, h1p, h2T, c2b);
    // out[b][o][p] = image + conv3(h2) + c3b   (CT orientation, float4 I/O)
    gemm_mfma<4, true, float, 64><<<dim3(C / 64, P / 128, B), 256, 0, stream>>>(
        h2T, c3w_b, out, P, C, C, C, C, P,
        (long)P * C, 0, (long)C * P, 1.f, c3b,
        nullptr, nullptr, nullptr, nullptr, image, (long)C * P, P, nullptr);
}